// Round 22
// baseline (289.240 us; speedup 1.0000x reference)
//
#include <hip/hip_runtime.h>
#include <hip/hip_fp16.h>

#define NNODES 100000
#define H1 4
#define C1 32
#define F0 64
#define F1 128   // H1*C1
#define C2 32
#define FOUT 8
#define SCAN_B 1024
#define NB 98      // ceil(NNODES/SCAN_B)
#define BCAP 64    // bucket ints per node: [0]=cursor, [1]=self, [2..]=edges

__device__ __forceinline__ float lrelu(float v) {
    return v > 0.f ? v : 0.2f * v;
}

// ================= bucket CSR build =================
// slots[n*BCAP+0] = cursor (init 2), slots[n*BCAP+1] = n (self-loop),
// real edges fill slots[n*BCAP + 2 .. cursor-1].

__global__ void k_binit(int* slots) {
    int n = blockIdx.x * blockDim.x + threadIdx.x;
    if (n >= NNODES) return;
    *(int2*)(slots + (size_t)n * BCAP) = make_int2(2, n);
}

// ---- FUSED: blocks [0,nbfill) do bfill; blocks [nbfill,..) do gemm1+att1 ----
// bfill FIRST so the latency-bound atomic chains launch immediately; the
// VALU-bound gemm blocks trail in and fill unused issue slots.
__global__ __launch_bounds__(256) void k_fused1(const int* __restrict__ ei, int E,
                                                int* slots,
                                                const float* __restrict__ x,
                                                const float* __restrict__ W1,
                                                const float* __restrict__ a_src1,
                                                const float* __restrict__ a_dst1,
                                                __half* __restrict__ h1h,
                                                float* __restrict__ as1,
                                                float* __restrict__ ad1,
                                                int nbfill) {
    __shared__ float xs[32 * F0];     // 8KB
    if ((int)blockIdx.x < nbfill) {
        int e = blockIdx.x * 256 + threadIdx.x;
        if (e >= E) return;
        int s = ei[e];
        int d = ei[E + e];
        int p = atomicAdd(&slots[(size_t)d * BCAP], 1);
        slots[(size_t)d * BCAP + p] = s;
        return;
    }
    int t = threadIdx.x;
    int row0 = ((int)blockIdx.x - nbfill) * 32;   // N % 32 == 0
    for (int i = t; i < 32 * F0; i += 256) xs[i] = x[(size_t)row0 * F0 + i];
    __syncthreads();
    int c2 = t & 63;                  // == lane (64-wide wave)
    int g = t >> 6;                   // wave id: rows g*8..g*8+7
    float a0[8], a1[8];
#pragma unroll
    for (int i = 0; i < 8; i++) { a0[i] = 0.f; a1[i] = 0.f; }
    for (int k = 0; k < F0; k++) {
        float2 w = *(const float2*)(W1 + (size_t)k * F1 + 2 * c2);
#pragma unroll
        for (int i = 0; i < 8; i++) {
            float xv = xs[(g * 8 + i) * F0 + k];
            a0[i] += xv * w.x;
            a1[i] += xv * w.y;
        }
    }
#pragma unroll
    for (int i = 0; i < 8; i++) {
        int row = row0 + g * 8 + i;
        *(__half2*)(h1h + (size_t)row * F1 + 2 * c2) = __floats2half2_rn(a0[i], a1[i]);
    }
    // ---- att1 epilogue: head h = c2>>4; lanes h*16..h*16+15 hold its 32 cols ----
    int h = c2 >> 4;
    int cc = 2 * (c2 & 15);           // within-head col of a0
    float s0 = a_src1[h * C1 + cc], s1 = a_src1[h * C1 + cc + 1];
    float d0 = a_dst1[h * C1 + cc], d1 = a_dst1[h * C1 + cc + 1];
    float sp[8], dp[8];
#pragma unroll
    for (int i = 0; i < 8; i++) {
        sp[i] = a0[i] * s0 + a1[i] * s1;
        dp[i] = a0[i] * d0 + a1[i] * d1;
    }
#pragma unroll
    for (int mask = 1; mask <= 8; mask <<= 1) {
#pragma unroll
        for (int i = 0; i < 8; i++) {
            sp[i] += __shfl_xor(sp[i], mask);
            dp[i] += __shfl_xor(dp[i], mask);
        }
    }
    if ((c2 & 15) == 0) {
#pragma unroll
        for (int i = 0; i < 8; i++) {
            int row = row0 + g * 8 + i;
            as1[row * 4 + h] = sp[i];
            ad1[row * 4 + h] = dp[i];
        }
    }
}

// ================= compact CSR build (fallback path) =================

__global__ void k_zero(int* rowptr) {
    int i = blockIdx.x * blockDim.x + threadIdx.x;
    if (i < NNODES) rowptr[i] = 1;   // self-loop pre-counted
}

__global__ void k_deg(const int* __restrict__ ei, int E, int* rowptr) {
    int e0 = (blockIdx.x * blockDim.x + threadIdx.x) * 4;
    if (e0 >= E) return;
    int4 d = *(const int4*)(ei + E + e0);
    atomicAdd(&rowptr[d.x], 1);
    atomicAdd(&rowptr[d.y], 1);
    atomicAdd(&rowptr[d.z], 1);
    atomicAdd(&rowptr[d.w], 1);
}

__global__ __launch_bounds__(SCAN_B) void k_scan_local(int* rowptr, int* bsum) {
    __shared__ int tmp[SCAN_B];
    int t = threadIdx.x;
    int i = blockIdx.x * SCAN_B + t;
    int v = (i < NNODES) ? rowptr[i] : 0;
    tmp[t] = v;
    for (int off = 1; off < SCAN_B; off <<= 1) {
        __syncthreads();
        int x = (t >= off) ? tmp[t - off] : 0;
        __syncthreads();
        tmp[t] += x;
    }
    __syncthreads();
    if (i < NNODES) rowptr[i] = tmp[t] - v;   // exclusive
    if (t == SCAN_B - 1) bsum[blockIdx.x] = tmp[t];
}

__global__ void k_scan_carry(int* bsum) {
    __shared__ int tmp[128];
    int t = threadIdx.x;
    tmp[t] = (t < NB) ? bsum[t] : 0;
    __syncthreads();
    if (t == 0) {
        int acc = 0;
        for (int b = 0; b < NB; b++) { int v = tmp[b]; tmp[b] = acc; acc += v; }
    }
    __syncthreads();
    if (t < NB) bsum[t] = tmp[t];
}

__global__ void k_scan_add(int* rowptr, const int* __restrict__ bsum) {
    int i = blockIdx.x * blockDim.x + threadIdx.x;
    if (i < NNODES) rowptr[i] += bsum[i >> 10];
}

__global__ void k_fill_self(int* rowptr, int* adj) {
    int n = blockIdx.x * blockDim.x + threadIdx.x;
    if (n >= NNODES) return;
    int pos = atomicAdd(&rowptr[n], 1);
    adj[pos] = n;
}

__global__ void k_fill(const int* __restrict__ ei, int E, int* rowptr, int* adj) {
    int e0 = (blockIdx.x * blockDim.x + threadIdx.x) * 4;
    if (e0 >= E) return;
    int4 s = *(const int4*)(ei + e0);
    int4 d = *(const int4*)(ei + E + e0);
    int p0 = atomicAdd(&rowptr[d.x], 1);
    int p1 = atomicAdd(&rowptr[d.y], 1);
    int p2 = atomicAdd(&rowptr[d.z], 1);
    int p3 = atomicAdd(&rowptr[d.w], 1);
    adj[p0] = s.x; adj[p1] = s.y; adj[p2] = s.z; adj[p3] = s.w;
}

// ---- fallback dense kernels (separate gemm1/att1) ----
__global__ __launch_bounds__(256) void k_gemm1(const float* __restrict__ x,
                                               const float* __restrict__ W1,
                                               __half* __restrict__ h1h) {
    __shared__ float xs[32 * F0];
    int t = threadIdx.x;
    int row0 = blockIdx.x * 32;
    for (int i = t; i < 32 * F0; i += 256) xs[i] = x[(size_t)row0 * F0 + i];
    __syncthreads();
    int c2 = t & 63;
    int g = t >> 6;
    float a0[8], a1[8];
#pragma unroll
    for (int i = 0; i < 8; i++) { a0[i] = 0.f; a1[i] = 0.f; }
    for (int k = 0; k < F0; k++) {
        float2 w = *(const float2*)(W1 + (size_t)k * F1 + 2 * c2);
#pragma unroll
        for (int i = 0; i < 8; i++) {
            float xv = xs[(g * 8 + i) * F0 + k];
            a0[i] += xv * w.x;
            a1[i] += xv * w.y;
        }
    }
#pragma unroll
    for (int i = 0; i < 8; i++) {
        int row = row0 + g * 8 + i;
        *(__half2*)(h1h + (size_t)row * F1 + 2 * c2) = __floats2half2_rn(a0[i], a1[i]);
    }
}

__global__ void k_att1(const __half* __restrict__ h1h, const float* __restrict__ a_src,
                       const float* __restrict__ a_dst, float* as1, float* ad1) {
    int i = blockIdx.x * blockDim.x + threadIdx.x;  // i = n*4+h
    if (i >= NNODES * H1) return;
    int h = i & 3;
    const __half2* hv = (const __half2*)(h1h + (size_t)(i >> 2) * F1 + h * C1);
    float s = 0.f, d = 0.f;
#pragma unroll
    for (int c = 0; c < C1 / 2; c++) {
        float2 v = __half22float2(hv[c]);
        s += v.x * a_src[h * C1 + 2 * c] + v.y * a_src[h * C1 + 2 * c + 1];
        d += v.x * a_dst[h * C1 + 2 * c] + v.y * a_dst[h * C1 + 2 * c + 1];
    }
    as1[i] = s; ad1[i] = d;
}

// ---- fused softmax+gather-aggregate, layer1 (fp16, 16B/lane gather) ----
// 2 nodes/block; 128 threads/node = 8 edge-slots x 16 lanes.
__global__ __launch_bounds__(256) void k_agg1(const int* __restrict__ idx,
                                              const int* __restrict__ rowptr,
                                              const int* __restrict__ cnt,
                                              const float* __restrict__ as1,
                                              const float* __restrict__ ad1,
                                              const __half* __restrict__ h1h,
                                              const float* __restrict__ b1,
                                              float* __restrict__ out1) {
    __shared__ float red[2][2][16][8];  // [node][wave][c][feat]  4KB
    __shared__ float sred[2][2][16];    // 256B
    int t = threadIdx.x;
    int nl = t >> 7;
    int n = blockIdx.x * 2 + nl;    // N even
    int u = t & 127;
    int slot = u >> 4;              // 0..7
    int c = u & 15;                 // 8-feature group: features 8c..8c+7
    int h = c >> 2;                 // head
    int start, end;
    if (cnt) {
        int cur = cnt[(size_t)n * BCAP];
        start = n * BCAP + 1; end = n * BCAP + cur;
    } else {
        start = (n == 0) ? 0 : rowptr[n - 1]; end = rowptr[n];
    }
    float adv = ad1[n * 4 + h];
    float acc[8];
#pragma unroll
    for (int i = 0; i < 8; i++) acc[i] = 0.f;
    float sacc = 0.f;
#pragma unroll 2
    for (int k = start + slot; k < end; k += 8) {
        int src = idx[k];
        float w = __expf(lrelu(as1[src * 4 + h] + adv));
        float4 raw = *(const float4*)(h1h + (size_t)src * F1 + c * 8);
        const __half2* hp = (const __half2*)&raw;
#pragma unroll
        for (int q = 0; q < 4; q++) {
            float2 f = __half22float2(hp[q]);
            acc[2 * q]     += w * f.x;
            acc[2 * q + 1] += w * f.y;
        }
        sacc += w;
    }
#pragma unroll
    for (int mask = 16; mask <= 32; mask <<= 1) {
#pragma unroll
        for (int i = 0; i < 8; i++) acc[i] += __shfl_xor(acc[i], mask);
        sacc += __shfl_xor(sacc, mask);
    }
    if ((u & 48) == 0) {   // one lane per (wave, c)
        int wv = u >> 6;
#pragma unroll
        for (int i = 0; i < 8; i++) red[nl][wv][c][i] = acc[i];
        sred[nl][wv][c] = sacc;
    }
    __syncthreads();
    if (u < 16) {          // c = u
        float s = sred[nl][0][u] + sred[nl][1][u];
        float rs = 1.f / (s + 1e-16f);
        float o[8];
#pragma unroll
        for (int i = 0; i < 8; i++) {
            float a = red[nl][0][u][i] + red[nl][1][u][i];
            float v = a * rs + b1[u * 8 + i];
            o[i] = v > 0.f ? v : 0.f;
        }
        float* dst = out1 + (size_t)n * F1 + u * 8;
        *(float4*)(dst)     = make_float4(o[0], o[1], o[2], o[3]);
        *(float4*)(dst + 4) = make_float4(o[4], o[5], o[6], o[7]);
    }
}

// ---- h2 = out1 @ W2 + att2 epilogue, output fp16 ----
__global__ __launch_bounds__(256) void k_gemm2a(const float* __restrict__ xin,
                                                const float* __restrict__ W2,
                                                const float* __restrict__ a_src2,
                                                const float* __restrict__ a_dst2,
                                                __half* __restrict__ h2h,
                                                float* __restrict__ as2,
                                                float* __restrict__ ad2) {
    __shared__ float wl[F1 * C2];   // 16KB
    __shared__ float xs[64 * F1];   // 32KB
    int t = threadIdx.x;
    int row0 = blockIdx.x * 64;
    for (int i = t; i < F1 * C2; i += 256) wl[i] = W2[i];
    for (int i = t; i < 64 * F1; i += 256) {
        int r = i >> 7, k = i & 127;
        int row = row0 + r;
        xs[i] = (row < NNODES) ? xin[(size_t)row * F1 + k] : 0.f;
    }
    __syncthreads();
    int c2 = t & 15;
    int g = t >> 4;
    float a0[4], a1[4];
#pragma unroll
    for (int i = 0; i < 4; i++) { a0[i] = 0.f; a1[i] = 0.f; }
    for (int k = 0; k < F1; k++) {
        float w0 = wl[k * C2 + 2 * c2];
        float w1 = wl[k * C2 + 2 * c2 + 1];
#pragma unroll
        for (int i = 0; i < 4; i++) {
            float xv = xs[(g * 4 + i) * F1 + k];
            a0[i] += xv * w0;
            a1[i] += xv * w1;
        }
    }
#pragma unroll
    for (int i = 0; i < 4; i++) {
        int row = row0 + g * 4 + i;
        if (row < NNODES)
            *(__half2*)(h2h + (size_t)row * C2 + 2 * c2) = __floats2half2_rn(a0[i], a1[i]);
    }
    // ---- att2 epilogue ----
    float s0 = a_src2[2 * c2], s1 = a_src2[2 * c2 + 1];
    float d0 = a_dst2[2 * c2], d1 = a_dst2[2 * c2 + 1];
    float sp[4], dp[4];
#pragma unroll
    for (int i = 0; i < 4; i++) {
        sp[i] = a0[i] * s0 + a1[i] * s1;
        dp[i] = a0[i] * d0 + a1[i] * d1;
    }
#pragma unroll
    for (int mask = 1; mask <= 8; mask <<= 1) {
#pragma unroll
        for (int i = 0; i < 4; i++) {
            sp[i] += __shfl_xor(sp[i], mask);
            dp[i] += __shfl_xor(dp[i], mask);
        }
    }
    if (c2 == 0) {
#pragma unroll
        for (int i = 0; i < 4; i++) {
            int row = row0 + g * 4 + i;
            if (row < NNODES) { as2[row] = sp[i]; ad2[row] = dp[i]; }
        }
    }
}

// ---- fused softmax+gather-aggregate + final linear, layer2 (fp16 gather) ----
// 8 nodes/block; 32 threads/node = 4 slots x 8 lanes; lane loads 2x__half2.
__global__ __launch_bounds__(256) void k_agg2f(const int* __restrict__ idx,
                                               const int* __restrict__ rowptr,
                                               const int* __restrict__ cnt,
                                               const float* __restrict__ as2,
                                               const float* __restrict__ ad2,
                                               const __half* __restrict__ h2h,
                                               const float* __restrict__ b2,
                                               const float* __restrict__ Wl,
                                               const float* __restrict__ bl,
                                               float* __restrict__ out) {
    int t = threadIdx.x;
    int n = blockIdx.x * 8 + (t >> 5);
    int u = t & 31;
    int slot = u >> 3;                  // 0..3
    int c = u & 7;                      // features 4c..4c+3
    int start, end;
    if (cnt) {
        int cur = cnt[(size_t)n * BCAP];
        start = n * BCAP + 1; end = n * BCAP + cur;
    } else {
        start = (n == 0) ? 0 : rowptr[n - 1]; end = rowptr[n];
    }
    float adv = ad2[n];
    float4 acc = make_float4(0.f, 0.f, 0.f, 0.f);
    float sacc = 0.f;
#pragma unroll 2
    for (int k = start + slot; k < end; k += 4) {
        int src = idx[k];
        float w = __expf(lrelu(as2[src] + adv));
        const __half2* hp = (const __half2*)(h2h + (size_t)src * C2 + c * 4);
        float2 f0 = __half22float2(hp[0]);
        float2 f1 = __half22float2(hp[1]);
        acc.x += w * f0.x; acc.y += w * f0.y;
        acc.z += w * f1.x; acc.w += w * f1.y;
        sacc += w;
    }
#pragma unroll
    for (int mask = 8; mask <= 16; mask <<= 1) {
        acc.x += __shfl_xor(acc.x, mask);
        acc.y += __shfl_xor(acc.y, mask);
        acc.z += __shfl_xor(acc.z, mask);
        acc.w += __shfl_xor(acc.w, mask);
        sacc  += __shfl_xor(sacc, mask);
    }
    if (slot == 0) {   // lanes u=0..7 hold the full out2 row (8 x float4)
        float rs = 1.f / (sacc + 1e-16f);
        float4 bv = *(const float4*)(b2 + c * 4);
        float4 o;
        o.x = acc.x * rs + bv.x; o.y = acc.y * rs + bv.y;
        o.z = acc.z * rs + bv.z; o.w = acc.w * rs + bv.w;
        o.x = o.x > 0.f ? o.x : 0.f;
        o.y = o.y > 0.f ? o.y : 0.f;
        o.z = o.z > 0.f ? o.z : 0.f;
        o.w = o.w > 0.f ? o.w : 0.f;
        float p[FOUT];
#pragma unroll
        for (int j = 0; j < FOUT; j++) {
            p[j] = o.x * Wl[(4 * c + 0) * FOUT + j]
                 + o.y * Wl[(4 * c + 1) * FOUT + j]
                 + o.z * Wl[(4 * c + 2) * FOUT + j]
                 + o.w * Wl[(4 * c + 3) * FOUT + j];
        }
#pragma unroll
        for (int mask = 1; mask <= 4; mask <<= 1) {
#pragma unroll
            for (int j = 0; j < FOUT; j++) p[j] += __shfl_xor(p[j], mask);
        }
        out[(size_t)n * FOUT + c] = p[c] + bl[c];
    }
}

extern "C" void kernel_launch(void* const* d_in, const int* in_sizes, int n_in,
                              void* d_out, int out_size, void* d_ws, size_t ws_size,
                              hipStream_t stream) {
    const float* x      = (const float*)d_in[0];
    const float* W1     = (const float*)d_in[1];
    const float* a_src1 = (const float*)d_in[2];
    const float* a_dst1 = (const float*)d_in[3];
    const float* b1     = (const float*)d_in[4];
    const float* W2     = (const float*)d_in[5];
    const float* a_src2 = (const float*)d_in[6];
    const float* a_dst2 = (const float*)d_in[7];
    const float* b2     = (const float*)d_in[8];
    const float* Wl     = (const float*)d_in[9];
    const float* bl     = (const float*)d_in[10];
    const int*   ei     = (const int*)d_in[11];
    int E = in_sizes[11] / 2;
    int Etot = E + NNODES;
    float* out = (float*)d_out;

    // ---- workspace layout ----
    // h1h (fp16, N*F1) | out1 (f32, N*F1) | as1 | ad1 | {slots} or {adj|rowptr|bsum}
    __half* h1h  = (__half*)d_ws;
    float* out1  = (float*)(h1h + (size_t)NNODES * F1);
    float* as1   = out1 + (size_t)NNODES * F1;
    float* ad1   = as1 + (size_t)NNODES * H1;
    int*   ibase = (int*)(ad1 + (size_t)NNODES * H1);
    // layer-2 aliases
    __half* h2h = h1h;
    float* as2 = as1;
    float* ad2 = ad1;

    size_t need_bucket = (size_t)NNODES * F1 * 2 + (size_t)NNODES * F1 * 4
                       + (size_t)NNODES * H1 * 8
                       + (size_t)NNODES * BCAP * 4;
    bool bucket = (ws_size >= need_bucket);

    const int B = 256;
    if (bucket) {
        int* slots = ibase;
        int ngemm = NNODES / 32;             // 3125
        int nbfill = (E + B - 1) / B;        // 6250
        k_binit<<<(NNODES + B - 1) / B, B, 0, stream>>>(slots);
        k_fused1<<<nbfill + ngemm, B, 0, stream>>>(ei, E, slots, x, W1,
                                                   a_src1, a_dst1, h1h, as1, ad1, nbfill);
        k_agg1<<<NNODES / 2, B, 0, stream>>>(slots, nullptr, slots, as1, ad1, h1h, b1, out1);
        k_gemm2a<<<(NNODES + 63) / 64, B, 0, stream>>>(out1, W2, a_src2, a_dst2, h2h, as2, ad2);
        k_agg2f<<<NNODES / 8, B, 0, stream>>>(slots, nullptr, slots, as2, ad2, h2h, b2, Wl, bl, out);
    } else {
        int* adj    = ibase;
        int* rowptr = adj + (size_t)Etot;
        int* bsum   = rowptr + NNODES;
        k_zero<<<(NNODES + B - 1) / B, B, 0, stream>>>(rowptr);
        k_deg<<<(E / 4 + B - 1) / B, B, 0, stream>>>(ei, E, rowptr);
        k_scan_local<<<NB, SCAN_B, 0, stream>>>(rowptr, bsum);
        k_scan_carry<<<1, 128, 0, stream>>>(bsum);
        k_scan_add<<<(NNODES + B - 1) / B, B, 0, stream>>>(rowptr, bsum);
        k_fill_self<<<(NNODES + B - 1) / B, B, 0, stream>>>(rowptr, adj);
        k_fill<<<(E / 4 + B - 1) / B, B, 0, stream>>>(ei, E, rowptr, adj);
        k_gemm1<<<NNODES / 32, B, 0, stream>>>(x, W1, h1h);
        k_att1<<<(NNODES * H1 + B - 1) / B, B, 0, stream>>>(h1h, a_src1, a_dst1, as1, ad1);
        k_agg1<<<NNODES / 2, B, 0, stream>>>(adj, rowptr, nullptr, as1, ad1, h1h, b1, out1);
        k_gemm2a<<<(NNODES + 63) / 64, B, 0, stream>>>(out1, W2, a_src2, a_dst2, h2h, as2, ad2);
        k_agg2f<<<NNODES / 8, B, 0, stream>>>(adj, rowptr, nullptr, as2, ad2, h2h, b2, Wl, bl, out);
    }
}

// Round 23
// 275.868 us; speedup vs baseline: 1.0485x; 1.0485x over previous
//
#include <hip/hip_runtime.h>
#include <hip/hip_fp16.h>

#define NNODES 100000
#define H1 4
#define C1 32
#define F0 64
#define F1 128   // H1*C1
#define C2 32
#define FOUT 8
#define SCAN_B 1024
#define NB 98      // ceil(NNODES/SCAN_B)
#define BCAP 64    // bucket ints per node: [0]=cursor, [1]=self, [2..]=edges

__device__ __forceinline__ float lrelu(float v) {
    return v > 0.f ? v : 0.2f * v;
}

// ================= bucket CSR build =================
// slots[n*BCAP+0] = cursor (init 2), slots[n*BCAP+1] = n (self-loop),
// real edges fill slots[n*BCAP + 2 .. cursor-1].

__global__ void k_binit(int* slots) {
    int n = blockIdx.x * blockDim.x + threadIdx.x;
    if (n >= NNODES) return;
    *(int2*)(slots + (size_t)n * BCAP) = make_int2(2, n);
}

// ---- FUSED: blocks [0,ngemm) do gemm1+att1; blocks [ngemm,..) do bfill ----
// Only 8KB static LDS (xs) so bfill blocks keep full wave occupancy.
// gemm1 reads W1 from global (L1-resident, coalesced float2/lane per k).
__global__ __launch_bounds__(256) void k_fused1(const int* __restrict__ ei, int E,
                                                int* slots,
                                                const float* __restrict__ x,
                                                const float* __restrict__ W1,
                                                const float* __restrict__ a_src1,
                                                const float* __restrict__ a_dst1,
                                                __half* __restrict__ h1h,
                                                float* __restrict__ as1,
                                                float* __restrict__ ad1,
                                                int ngemm) {
    __shared__ float xs[32 * F0];     // 8KB
    if ((int)blockIdx.x >= ngemm) {
        int e = ((int)blockIdx.x - ngemm) * 256 + threadIdx.x;
        if (e >= E) return;
        int s = ei[e];
        int d = ei[E + e];
        int p = atomicAdd(&slots[(size_t)d * BCAP], 1);
        slots[(size_t)d * BCAP + p] = s;
        return;
    }
    int t = threadIdx.x;
    int row0 = blockIdx.x * 32;       // N % 32 == 0
    for (int i = t; i < 32 * F0; i += 256) xs[i] = x[(size_t)row0 * F0 + i];
    __syncthreads();
    int c2 = t & 63;                  // == lane (64-wide wave)
    int g = t >> 6;                   // wave id: rows g*8..g*8+7
    float a0[8], a1[8];
#pragma unroll
    for (int i = 0; i < 8; i++) { a0[i] = 0.f; a1[i] = 0.f; }
    for (int k = 0; k < F0; k++) {
        float2 w = *(const float2*)(W1 + (size_t)k * F1 + 2 * c2);
#pragma unroll
        for (int i = 0; i < 8; i++) {
            float xv = xs[(g * 8 + i) * F0 + k];
            a0[i] += xv * w.x;
            a1[i] += xv * w.y;
        }
    }
#pragma unroll
    for (int i = 0; i < 8; i++) {
        int row = row0 + g * 8 + i;
        *(__half2*)(h1h + (size_t)row * F1 + 2 * c2) = __floats2half2_rn(a0[i], a1[i]);
    }
    // ---- att1 epilogue: head h = c2>>4; lanes h*16..h*16+15 hold its 32 cols ----
    int h = c2 >> 4;
    int cc = 2 * (c2 & 15);           // within-head col of a0
    float s0 = a_src1[h * C1 + cc], s1 = a_src1[h * C1 + cc + 1];
    float d0 = a_dst1[h * C1 + cc], d1 = a_dst1[h * C1 + cc + 1];
    float sp[8], dp[8];
#pragma unroll
    for (int i = 0; i < 8; i++) {
        sp[i] = a0[i] * s0 + a1[i] * s1;
        dp[i] = a0[i] * d0 + a1[i] * d1;
    }
#pragma unroll
    for (int mask = 1; mask <= 8; mask <<= 1) {
#pragma unroll
        for (int i = 0; i < 8; i++) {
            sp[i] += __shfl_xor(sp[i], mask);
            dp[i] += __shfl_xor(dp[i], mask);
        }
    }
    if ((c2 & 15) == 0) {
#pragma unroll
        for (int i = 0; i < 8; i++) {
            int row = row0 + g * 8 + i;
            as1[row * 4 + h] = sp[i];
            ad1[row * 4 + h] = dp[i];
        }
    }
}

// ================= compact CSR build (fallback path) =================

__global__ void k_zero(int* rowptr) {
    int i = blockIdx.x * blockDim.x + threadIdx.x;
    if (i < NNODES) rowptr[i] = 1;   // self-loop pre-counted
}

__global__ void k_deg(const int* __restrict__ ei, int E, int* rowptr) {
    int e0 = (blockIdx.x * blockDim.x + threadIdx.x) * 4;
    if (e0 >= E) return;
    int4 d = *(const int4*)(ei + E + e0);
    atomicAdd(&rowptr[d.x], 1);
    atomicAdd(&rowptr[d.y], 1);
    atomicAdd(&rowptr[d.z], 1);
    atomicAdd(&rowptr[d.w], 1);
}

__global__ __launch_bounds__(SCAN_B) void k_scan_local(int* rowptr, int* bsum) {
    __shared__ int tmp[SCAN_B];
    int t = threadIdx.x;
    int i = blockIdx.x * SCAN_B + t;
    int v = (i < NNODES) ? rowptr[i] : 0;
    tmp[t] = v;
    for (int off = 1; off < SCAN_B; off <<= 1) {
        __syncthreads();
        int x = (t >= off) ? tmp[t - off] : 0;
        __syncthreads();
        tmp[t] += x;
    }
    __syncthreads();
    if (i < NNODES) rowptr[i] = tmp[t] - v;   // exclusive
    if (t == SCAN_B - 1) bsum[blockIdx.x] = tmp[t];
}

__global__ void k_scan_carry(int* bsum) {
    __shared__ int tmp[128];
    int t = threadIdx.x;
    tmp[t] = (t < NB) ? bsum[t] : 0;
    __syncthreads();
    if (t == 0) {
        int acc = 0;
        for (int b = 0; b < NB; b++) { int v = tmp[b]; tmp[b] = acc; acc += v; }
    }
    __syncthreads();
    if (t < NB) bsum[t] = tmp[t];
}

__global__ void k_scan_add(int* rowptr, const int* __restrict__ bsum) {
    int i = blockIdx.x * blockDim.x + threadIdx.x;
    if (i < NNODES) rowptr[i] += bsum[i >> 10];
}

__global__ void k_fill_self(int* rowptr, int* adj) {
    int n = blockIdx.x * blockDim.x + threadIdx.x;
    if (n >= NNODES) return;
    int pos = atomicAdd(&rowptr[n], 1);
    adj[pos] = n;
}

__global__ void k_fill(const int* __restrict__ ei, int E, int* rowptr, int* adj) {
    int e0 = (blockIdx.x * blockDim.x + threadIdx.x) * 4;
    if (e0 >= E) return;
    int4 s = *(const int4*)(ei + e0);
    int4 d = *(const int4*)(ei + E + e0);
    int p0 = atomicAdd(&rowptr[d.x], 1);
    int p1 = atomicAdd(&rowptr[d.y], 1);
    int p2 = atomicAdd(&rowptr[d.z], 1);
    int p3 = atomicAdd(&rowptr[d.w], 1);
    adj[p0] = s.x; adj[p1] = s.y; adj[p2] = s.z; adj[p3] = s.w;
}

// ---- fallback dense kernels (separate gemm1/att1) ----
__global__ __launch_bounds__(256) void k_gemm1(const float* __restrict__ x,
                                               const float* __restrict__ W1,
                                               __half* __restrict__ h1h) {
    __shared__ float xs[32 * F0];
    int t = threadIdx.x;
    int row0 = blockIdx.x * 32;
    for (int i = t; i < 32 * F0; i += 256) xs[i] = x[(size_t)row0 * F0 + i];
    __syncthreads();
    int c2 = t & 63;
    int g = t >> 6;
    float a0[8], a1[8];
#pragma unroll
    for (int i = 0; i < 8; i++) { a0[i] = 0.f; a1[i] = 0.f; }
    for (int k = 0; k < F0; k++) {
        float2 w = *(const float2*)(W1 + (size_t)k * F1 + 2 * c2);
#pragma unroll
        for (int i = 0; i < 8; i++) {
            float xv = xs[(g * 8 + i) * F0 + k];
            a0[i] += xv * w.x;
            a1[i] += xv * w.y;
        }
    }
#pragma unroll
    for (int i = 0; i < 8; i++) {
        int row = row0 + g * 8 + i;
        *(__half2*)(h1h + (size_t)row * F1 + 2 * c2) = __floats2half2_rn(a0[i], a1[i]);
    }
}

__global__ void k_att1(const __half* __restrict__ h1h, const float* __restrict__ a_src,
                       const float* __restrict__ a_dst, float* as1, float* ad1) {
    int i = blockIdx.x * blockDim.x + threadIdx.x;  // i = n*4+h
    if (i >= NNODES * H1) return;
    int h = i & 3;
    const __half2* hv = (const __half2*)(h1h + (size_t)(i >> 2) * F1 + h * C1);
    float s = 0.f, d = 0.f;
#pragma unroll
    for (int c = 0; c < C1 / 2; c++) {
        float2 v = __half22float2(hv[c]);
        s += v.x * a_src[h * C1 + 2 * c] + v.y * a_src[h * C1 + 2 * c + 1];
        d += v.x * a_dst[h * C1 + 2 * c] + v.y * a_dst[h * C1 + 2 * c + 1];
    }
    as1[i] = s; ad1[i] = d;
}

// ---- fused softmax+gather-aggregate, layer1 (fp16, 16B/lane gather) ----
// 2 nodes/block; 128 threads/node = 8 edge-slots x 16 lanes.
__global__ __launch_bounds__(256) void k_agg1(const int* __restrict__ idx,
                                              const int* __restrict__ rowptr,
                                              const int* __restrict__ cnt,
                                              const float* __restrict__ as1,
                                              const float* __restrict__ ad1,
                                              const __half* __restrict__ h1h,
                                              const float* __restrict__ b1,
                                              float* __restrict__ out1) {
    __shared__ float red[2][2][16][8];  // [node][wave][c][feat]  4KB
    __shared__ float sred[2][2][16];    // 256B
    int t = threadIdx.x;
    int nl = t >> 7;
    int n = blockIdx.x * 2 + nl;    // N even
    int u = t & 127;
    int slot = u >> 4;              // 0..7
    int c = u & 15;                 // 8-feature group: features 8c..8c+7
    int h = c >> 2;                 // head
    int start, end;
    if (cnt) {
        int cur = cnt[(size_t)n * BCAP];
        start = n * BCAP + 1; end = n * BCAP + cur;
    } else {
        start = (n == 0) ? 0 : rowptr[n - 1]; end = rowptr[n];
    }
    float adv = ad1[n * 4 + h];
    float acc[8];
#pragma unroll
    for (int i = 0; i < 8; i++) acc[i] = 0.f;
    float sacc = 0.f;
#pragma unroll 2
    for (int k = start + slot; k < end; k += 8) {
        int src = idx[k];
        float w = __expf(lrelu(as1[src * 4 + h] + adv));
        float4 raw = *(const float4*)(h1h + (size_t)src * F1 + c * 8);
        const __half2* hp = (const __half2*)&raw;
#pragma unroll
        for (int q = 0; q < 4; q++) {
            float2 f = __half22float2(hp[q]);
            acc[2 * q]     += w * f.x;
            acc[2 * q + 1] += w * f.y;
        }
        sacc += w;
    }
#pragma unroll
    for (int mask = 16; mask <= 32; mask <<= 1) {
#pragma unroll
        for (int i = 0; i < 8; i++) acc[i] += __shfl_xor(acc[i], mask);
        sacc += __shfl_xor(sacc, mask);
    }
    if ((u & 48) == 0) {   // one lane per (wave, c)
        int wv = u >> 6;
#pragma unroll
        for (int i = 0; i < 8; i++) red[nl][wv][c][i] = acc[i];
        sred[nl][wv][c] = sacc;
    }
    __syncthreads();
    if (u < 16) {          // c = u
        float s = sred[nl][0][u] + sred[nl][1][u];
        float rs = 1.f / (s + 1e-16f);
        float o[8];
#pragma unroll
        for (int i = 0; i < 8; i++) {
            float a = red[nl][0][u][i] + red[nl][1][u][i];
            float v = a * rs + b1[u * 8 + i];
            o[i] = v > 0.f ? v : 0.f;
        }
        float* dst = out1 + (size_t)n * F1 + u * 8;
        *(float4*)(dst)     = make_float4(o[0], o[1], o[2], o[3]);
        *(float4*)(dst + 4) = make_float4(o[4], o[5], o[6], o[7]);
    }
}

// ---- h2 = out1 @ W2 + att2 epilogue, output fp16 ----
__global__ __launch_bounds__(256) void k_gemm2a(const float* __restrict__ xin,
                                                const float* __restrict__ W2,
                                                const float* __restrict__ a_src2,
                                                const float* __restrict__ a_dst2,
                                                __half* __restrict__ h2h,
                                                float* __restrict__ as2,
                                                float* __restrict__ ad2) {
    __shared__ float wl[F1 * C2];   // 16KB
    __shared__ float xs[64 * F1];   // 32KB
    int t = threadIdx.x;
    int row0 = blockIdx.x * 64;
    for (int i = t; i < F1 * C2; i += 256) wl[i] = W2[i];
    for (int i = t; i < 64 * F1; i += 256) {
        int r = i >> 7, k = i & 127;
        int row = row0 + r;
        xs[i] = (row < NNODES) ? xin[(size_t)row * F1 + k] : 0.f;
    }
    __syncthreads();
    int c2 = t & 15;
    int g = t >> 4;
    float a0[4], a1[4];
#pragma unroll
    for (int i = 0; i < 4; i++) { a0[i] = 0.f; a1[i] = 0.f; }
    for (int k = 0; k < F1; k++) {
        float w0 = wl[k * C2 + 2 * c2];
        float w1 = wl[k * C2 + 2 * c2 + 1];
#pragma unroll
        for (int i = 0; i < 4; i++) {
            float xv = xs[(g * 4 + i) * F1 + k];
            a0[i] += xv * w0;
            a1[i] += xv * w1;
        }
    }
#pragma unroll
    for (int i = 0; i < 4; i++) {
        int row = row0 + g * 4 + i;
        if (row < NNODES)
            *(__half2*)(h2h + (size_t)row * C2 + 2 * c2) = __floats2half2_rn(a0[i], a1[i]);
    }
    // ---- att2 epilogue ----
    float s0 = a_src2[2 * c2], s1 = a_src2[2 * c2 + 1];
    float d0 = a_dst2[2 * c2], d1 = a_dst2[2 * c2 + 1];
    float sp[4], dp[4];
#pragma unroll
    for (int i = 0; i < 4; i++) {
        sp[i] = a0[i] * s0 + a1[i] * s1;
        dp[i] = a0[i] * d0 + a1[i] * d1;
    }
#pragma unroll
    for (int mask = 1; mask <= 8; mask <<= 1) {
#pragma unroll
        for (int i = 0; i < 4; i++) {
            sp[i] += __shfl_xor(sp[i], mask);
            dp[i] += __shfl_xor(dp[i], mask);
        }
    }
    if (c2 == 0) {
#pragma unroll
        for (int i = 0; i < 4; i++) {
            int row = row0 + g * 4 + i;
            if (row < NNODES) { as2[row] = sp[i]; ad2[row] = dp[i]; }
        }
    }
}

// ---- fused softmax+gather-aggregate + final linear, layer2 (fp16 gather) ----
// 8 nodes/block; 32 threads/node = 4 slots x 8 lanes; lane loads 2x__half2.
__global__ __launch_bounds__(256) void k_agg2f(const int* __restrict__ idx,
                                               const int* __restrict__ rowptr,
                                               const int* __restrict__ cnt,
                                               const float* __restrict__ as2,
                                               const float* __restrict__ ad2,
                                               const __half* __restrict__ h2h,
                                               const float* __restrict__ b2,
                                               const float* __restrict__ Wl,
                                               const float* __restrict__ bl,
                                               float* __restrict__ out) {
    int t = threadIdx.x;
    int n = blockIdx.x * 8 + (t >> 5);
    int u = t & 31;
    int slot = u >> 3;                  // 0..3
    int c = u & 7;                      // features 4c..4c+3
    int start, end;
    if (cnt) {
        int cur = cnt[(size_t)n * BCAP];
        start = n * BCAP + 1; end = n * BCAP + cur;
    } else {
        start = (n == 0) ? 0 : rowptr[n - 1]; end = rowptr[n];
    }
    float adv = ad2[n];
    float4 acc = make_float4(0.f, 0.f, 0.f, 0.f);
    float sacc = 0.f;
#pragma unroll 2
    for (int k = start + slot; k < end; k += 4) {
        int src = idx[k];
        float w = __expf(lrelu(as2[src] + adv));
        const __half2* hp = (const __half2*)(h2h + (size_t)src * C2 + c * 4);
        float2 f0 = __half22float2(hp[0]);
        float2 f1 = __half22float2(hp[1]);
        acc.x += w * f0.x; acc.y += w * f0.y;
        acc.z += w * f1.x; acc.w += w * f1.y;
        sacc += w;
    }
#pragma unroll
    for (int mask = 8; mask <= 16; mask <<= 1) {
        acc.x += __shfl_xor(acc.x, mask);
        acc.y += __shfl_xor(acc.y, mask);
        acc.z += __shfl_xor(acc.z, mask);
        acc.w += __shfl_xor(acc.w, mask);
        sacc  += __shfl_xor(sacc, mask);
    }
    if (slot == 0) {   // lanes u=0..7 hold the full out2 row (8 x float4)
        float rs = 1.f / (sacc + 1e-16f);
        float4 bv = *(const float4*)(b2 + c * 4);
        float4 o;
        o.x = acc.x * rs + bv.x; o.y = acc.y * rs + bv.y;
        o.z = acc.z * rs + bv.z; o.w = acc.w * rs + bv.w;
        o.x = o.x > 0.f ? o.x : 0.f;
        o.y = o.y > 0.f ? o.y : 0.f;
        o.z = o.z > 0.f ? o.z : 0.f;
        o.w = o.w > 0.f ? o.w : 0.f;
        float p[FOUT];
#pragma unroll
        for (int j = 0; j < FOUT; j++) {
            p[j] = o.x * Wl[(4 * c + 0) * FOUT + j]
                 + o.y * Wl[(4 * c + 1) * FOUT + j]
                 + o.z * Wl[(4 * c + 2) * FOUT + j]
                 + o.w * Wl[(4 * c + 3) * FOUT + j];
        }
#pragma unroll
        for (int mask = 1; mask <= 4; mask <<= 1) {
#pragma unroll
            for (int j = 0; j < FOUT; j++) p[j] += __shfl_xor(p[j], mask);
        }
        out[(size_t)n * FOUT + c] = p[c] + bl[c];
    }
}

extern "C" void kernel_launch(void* const* d_in, const int* in_sizes, int n_in,
                              void* d_out, int out_size, void* d_ws, size_t ws_size,
                              hipStream_t stream) {
    const float* x      = (const float*)d_in[0];
    const float* W1     = (const float*)d_in[1];
    const float* a_src1 = (const float*)d_in[2];
    const float* a_dst1 = (const float*)d_in[3];
    const float* b1     = (const float*)d_in[4];
    const float* W2     = (const float*)d_in[5];
    const float* a_src2 = (const float*)d_in[6];
    const float* a_dst2 = (const float*)d_in[7];
    const float* b2     = (const float*)d_in[8];
    const float* Wl     = (const float*)d_in[9];
    const float* bl     = (const float*)d_in[10];
    const int*   ei     = (const int*)d_in[11];
    int E = in_sizes[11] / 2;
    int Etot = E + NNODES;
    float* out = (float*)d_out;

    // ---- workspace layout ----
    // h1h (fp16, N*F1) | out1 (f32, N*F1) | as1 | ad1 | {slots} or {adj|rowptr|bsum}
    __half* h1h  = (__half*)d_ws;
    float* out1  = (float*)(h1h + (size_t)NNODES * F1);
    float* as1   = out1 + (size_t)NNODES * F1;
    float* ad1   = as1 + (size_t)NNODES * H1;
    int*   ibase = (int*)(ad1 + (size_t)NNODES * H1);
    // layer-2 aliases
    __half* h2h = h1h;
    float* as2 = as1;
    float* ad2 = ad1;

    size_t need_bucket = (size_t)NNODES * F1 * 2 + (size_t)NNODES * F1 * 4
                       + (size_t)NNODES * H1 * 8
                       + (size_t)NNODES * BCAP * 4;
    bool bucket = (ws_size >= need_bucket);

    const int B = 256;
    if (bucket) {
        int* slots = ibase;
        int ngemm = NNODES / 32;             // 3125
        int nbfill = (E + B - 1) / B;        // 6250
        k_binit<<<(NNODES + B - 1) / B, B, 0, stream>>>(slots);
        k_fused1<<<ngemm + nbfill, B, 0, stream>>>(ei, E, slots, x, W1,
                                                   a_src1, a_dst1, h1h, as1, ad1, ngemm);
        k_agg1<<<NNODES / 2, B, 0, stream>>>(slots, nullptr, slots, as1, ad1, h1h, b1, out1);
        k_gemm2a<<<(NNODES + 63) / 64, B, 0, stream>>>(out1, W2, a_src2, a_dst2, h2h, as2, ad2);
        k_agg2f<<<NNODES / 8, B, 0, stream>>>(slots, nullptr, slots, as2, ad2, h2h, b2, Wl, bl, out);
    } else {
        int* adj    = ibase;
        int* rowptr = adj + (size_t)Etot;
        int* bsum   = rowptr + NNODES;
        k_zero<<<(NNODES + B - 1) / B, B, 0, stream>>>(rowptr);
        k_deg<<<(E / 4 + B - 1) / B, B, 0, stream>>>(ei, E, rowptr);
        k_scan_local<<<NB, SCAN_B, 0, stream>>>(rowptr, bsum);
        k_scan_carry<<<1, 128, 0, stream>>>(bsum);
        k_scan_add<<<(NNODES + B - 1) / B, B, 0, stream>>>(rowptr, bsum);
        k_fill_self<<<(NNODES + B - 1) / B, B, 0, stream>>>(rowptr, adj);
        k_fill<<<(E / 4 + B - 1) / B, B, 0, stream>>>(ei, E, rowptr, adj);
        k_gemm1<<<NNODES / 32, B, 0, stream>>>(x, W1, h1h);
        k_att1<<<(NNODES * H1 + B - 1) / B, B, 0, stream>>>(h1h, a_src1, a_dst1, as1, ad1);
        k_agg1<<<NNODES / 2, B, 0, stream>>>(adj, rowptr, nullptr, as1, ad1, h1h, b1, out1);
        k_gemm2a<<<(NNODES + 63) / 64, B, 0, stream>>>(out1, W2, a_src2, a_dst2, h2h, as2, ad2);
        k_agg2f<<<NNODES / 8, B, 0, stream>>>(adj, rowptr, nullptr, as2, ad2, h2h, b2, Wl, bl, out);
    }
}